// Round 1
// baseline (48418.176 us; speedup 1.0000x reference)
//
#include <hip/hip_runtime.h>
#include <hip/hip_cooperative_groups.h>

namespace cg = cooperative_groups;

// ---------------------------------------------------------------------------
// Persistent-cooperative RNN: 1000 Euler steps inside ONE kernel.
//   - W re-chunked into 26 LDS-resident chunks (<=157KB each, k-major,
//     stride R+4 for bank rotation), split by output rows so each block owns
//     complete output rows (no cross-block K reduction).
//   - grid = 26 chunks x 8 batch-groups (4 batches each) = 208 blocks
//     (<=256 CUs, 1 block/CU at this LDS size -> cooperative-resident).
//   - x state lives in registers for the whole run (block-private).
//   - h double-buffered in ws; one grid.sync() per step.
// ws layout (floats): [Wc 836736][hA 53632][hB 53632] = 3.78 MB
// ---------------------------------------------------------------------------

#define TOTS   1676
#define NSTEP  1000
#define DTC    0.01f
#define SCALE  1.41421356237e-3f   // sqrt(2*0.01)*0.01
#define NCHUNK 26
#define GRIDSZ 208                 // 26 * 8
#define WTOTAL 836736
#define HA_OFF 836736
#define HB_OFF 890368
#define PSTR   20                  // pacc row stride (floats), bank-rotated
#define LDSB   157184              // max over chunks: thal/alm = 39296 floats

// region params: 0 str, 1 gpe, 2 stn, 3 snr, 4 thal, 5 alm, 6 fsi
__device__ const int   r_R[7]     = {32, 256, 128, 64, 64, 64, 32};
__device__ const int   r_Kper[7]  = {29, 32, 32, 25, 33, 33, 21};
__device__ const int   r_K[7]     = {908, 128, 256, 384, 512, 512, 652};
__device__ const int   r_Kpad[7]  = {928, 128, 256, 400, 528, 528, 672};
__device__ const int   r_strd[7]  = {36, 260, 132, 68, 68, 68, 36};
__device__ const int   r_jbase[7] = {0, 256, 512, 768, 1024, 1280, 1600};
__device__ const float r_tonic[7] = {0.f, 1.f, 1.f, 0.f, 1.f, 0.f, 0.f};
__device__ const int   r_nseg[7]  = {5, 1, 1, 2, 2, 2, 4};
__device__ const int   r_ss[7][5] = {{0,1024,1280,1536,1600},{128,0,0,0,0},{256,0,0,0,0},
                                     {0,512,0,0,0},{768,1280,0,0,0},{1024,1280,0,0,0},
                                     {1024,1280,1536,1600,0}};
__device__ const int   r_sl[7][5] = {{256,256,256,64,76},{128,0,0,0,0},{256,0,0,0,0},
                                     {128,256,0,0,0},{256,256,0,0,0},{256,256,0,0,0},
                                     {256,256,64,76,0}};

__device__ const int c_reg[NCHUNK]   = {0,0,0,0,0,0,0,0, 1, 2,2, 3,3,3,3, 4,4,4,4, 5,5,5,5, 6,6,6};
__device__ const int c_rowb[NCHUNK]  = {0,32,64,96,128,160,192,224, 0, 0,128,
                                        0,64,128,192, 0,64,128,192, 0,64,128,192, 0,32,64};
__device__ const int c_rreal[NCHUNK] = {32,32,32,32,32,32,32,32, 256, 128,128,
                                        64,64,64,64, 64,64,64,64, 64,64,64,64, 32,32,12};
__device__ const int c_woff[NCHUNK]  = {0,33408,66816,100224,133632,167040,200448,233856,
                                        267264, 300544,334336,
                                        368128,395328,422528,449728,
                                        476928,512832,548736,584640,
                                        620544,656448,692352,728256,
                                        764160,788352,812544};

__global__ __launch_bounds__(256)
void build_kernel(const float* __restrict__ sparse,   const float* __restrict__ str2str,
                  const float* __restrict__ thal2alm, const float* __restrict__ thal2str,
                  const float* __restrict__ alm2alm,  const float* __restrict__ alm2str,
                  const float* __restrict__ alm2thal, const float* __restrict__ str2snr,
                  const float* __restrict__ str2gpe,  const float* __restrict__ gpe2stn,
                  const float* __restrict__ stn2snr,  const float* __restrict__ snr2thal,
                  const float* __restrict__ fsi2str,  const float* __restrict__ thal2fsi,
                  const float* __restrict__ alm2fsi,  const float* __restrict__ iti2fsi,
                  const float* __restrict__ fsi2fsi,  const float* __restrict__ inp_str,
                  float* __restrict__ ws)
{
  int idx = blockIdx.x * 256 + threadIdx.x;
  if (idx >= WTOTAL) return;
  int c = 0;
  for (int cc = NCHUNK - 1; cc > 0; --cc) { if (idx >= c_woff[cc]) { c = cc; break; } }
  const int reg  = c_reg[c];
  const int strd = r_strd[reg];
  const int R    = r_R[reg];
  const int K    = r_K[reg];
  int rel = idx - c_woff[c];
  int k   = rel / strd;
  int rr  = rel - k * strd;
  float v = 0.f;
  if (rr < R && k < K) {
    int il = c_rowb[c] + rr;
    int j = 0, kk = k;
    for (int s = 0; s < r_nseg[reg]; ++s) {
      int len = r_sl[reg][s];
      if (kk < len) { j = r_ss[reg][s] + kk; break; }
      kk -= len;
    }
    switch (reg) {
      case 0: {
        if (j < 256) {
          bool same = (il < 128) == (j < 128);
          float w = fmaxf(str2str[il * 256 + j], 0.f);
          v = same ? -(sparse[il * 256 + j] * w) : 0.f;
        } else if (j < 1280) v = fmaxf(thal2str[il * 256 + (j - 1024)], 0.f);
        else if (j < 1536) { int lj = j - 1280; v = (lj < 180) ? fmaxf(alm2str[il * 256 + lj], 0.f) : 0.f; }
        else if (j < 1600) v = fmaxf(inp_str[il * 64 + (j - 1536)], 0.f);
        else               v = -fmaxf(fsi2str[il * 76 + (j - 1600)], 0.f);
      } break;
      case 1: v = -fmaxf(str2gpe[il * 256 + j], 0.f); break;
      case 2: v = -fmaxf(gpe2stn[il * 256 + (j - 256)], 0.f); break;
      case 3: v = (j < 128) ? -fmaxf(str2snr[il * 256 + j], 0.f)
                            :  fmaxf(stn2snr[il * 256 + (j - 512)], 0.f); break;
      case 4:
        if (j < 1024) v = -fmaxf(snr2thal[il * 256 + (j - 768)], 0.f);
        else { int lj = j - 1280; v = (lj < 180) ? fmaxf(alm2thal[il * 256 + lj], 0.f) : 0.f; }
        break;
      case 5:
        if (j < 1280) v = fmaxf(thal2alm[il * 256 + (j - 1024)], 0.f);
        else { int lj = j - 1280; float w = fmaxf(alm2alm[il * 256 + lj], 0.f); v = (lj >= 180) ? -w : w; }
        break;
      default:
        if (il < 76) {
          if (j < 1280)      v =  fmaxf(thal2fsi[il * 256 + (j - 1024)], 0.f);
          else if (j < 1536) v =  fmaxf(alm2fsi[il * 256 + (j - 1280)], 0.f);
          else if (j < 1600) v =  fmaxf(iti2fsi[il * 64 + (j - 1536)], 0.f);
          else               v = -fmaxf(fsi2fsi[il * 76 + (j - 1600)], 0.f);
        }
        break;
    }
  }
  ws[idx] = v;
}

__global__ __launch_bounds__(256, 1)
void rnn_persistent(const float* __restrict__ inp,   const float* __restrict__ cue,
                    const float* __restrict__ hn,    const float* __restrict__ xn,
                    const float* __restrict__ inhib, const float* __restrict__ noise,
                    float* __restrict__ ws,          float* __restrict__ out)
{
  extern __shared__ float lds[];
  const int tid = threadIdx.x;
  const int c   = blockIdx.x % NCHUNK;
  const int b0  = (blockIdx.x / NCHUNK) * 4;
  const int reg  = c_reg[c];
  const int R    = r_R[reg];
  const int Kper = r_Kper[reg];
  const int K    = r_K[reg];
  const int Kpad = r_Kpad[reg];
  const int strd = r_strd[reg];
  const int RG   = R >> 2;
  const int rgsh = (R == 32) ? 3 : (R == 64) ? 4 : (R == 128) ? 5 : 6;
  const int jout0 = r_jbase[reg] + c_rowb[c];
  const int rreal = c_rreal[c];
  const float tonic = r_tonic[reg];
  const bool isthal = (reg == 4);
  const bool hasiti = (c == 25);

  float* ldsW = lds;
  float* ldsH = lds + Kpad * strd;       // float4[Kpad]: h[k][4 batches]
  float* pacc = ldsH + Kpad * 4;         // [4 waves][RG][PSTR]

  // ---- one-time: W chunk -> LDS; zero h pad region
  {
    const float* wg = ws + c_woff[c];
    const int n = Kpad * strd;           // always divisible by 4
    for (int i = tid * 4; i < n; i += 1024)
      *(float4*)&ldsW[i] = *(const float4*)&wg[i];
  }
  for (int i = tid; i < Kpad; i += 256)
    *(float4*)&ldsH[i * 4] = make_float4(0.f, 0.f, 0.f, 0.f);

  // ---- output ownership: fid = tid + 256*it -> (row = tid/4 + 64*it, b = tid%4)
  const int b    = tid & 3;
  const int bb   = b0 + b;
  const int row0 = tid >> 2;
  const int R4   = R * 4;
  bool act[4]; int hoff[4]; size_t obase[4]; float xreg[4];
#pragma unroll
  for (int it = 0; it < 4; ++it) {
    int fid = tid + it * 256;
    int row = row0 + it * 64;
    act[it] = (fid < R4) && (row < rreal);
    int j = jout0 + row;
    hoff[it]  = bb * TOTS + j;
    obase[it] = (size_t)bb * NSTEP * TOTS + j;
    xreg[it]  = act[it] ? xn[hoff[it]] : 0.f;
  }
  int hoff_i = 0; size_t obase_i = 0; float xreg_i = 0.f;
  if (hasiti) {                       // iti rows 1536..1599, all 256 threads
    int j = 1536 + row0;
    hoff_i  = bb * TOTS + j;
    obase_i = (size_t)bb * NSTEP * TOTS + j;
    xreg_i  = xn[hoff_i];
  }

  const int rg = tid & (RG - 1);
  const int ks = tid >> rgsh;
  const int wv = tid >> 6;

  cg::grid_group grid = cg::this_grid();

  for (int t = 0; t < NSTEP; ++t) {
    const float* __restrict__ hsrc = (t == 0) ? hn : (ws + ((t & 1) ? HB_OFF : HA_OFF));
    float* __restrict__ hdst = ws + ((t & 1) ? HA_OFF : HB_OFF);

    // ---- stage h[k][b0..b0+3] into LDS (compacted k)
    for (int u = tid; u < K; u += 256) {
      int j = 0, kk = u;
      for (int s = 0; s < r_nseg[reg]; ++s) {
        int len = r_sl[reg][s];
        if (kk < len) { j = r_ss[reg][s] + kk; break; }
        kk -= len;
      }
      const float* hp = hsrc + j;
      float4 hv;
      hv.x = hp[(b0 + 0) * TOTS];
      hv.y = hp[(b0 + 1) * TOTS];
      hv.z = hp[(b0 + 2) * TOTS];
      hv.w = hp[(b0 + 3) * TOTS];
      *(float4*)&ldsH[u * 4] = hv;
    }

    // ---- prefetch epilogue operands (hide HBM latency behind compute)
    float inh_p[4], noi_p[4];
#pragma unroll
    for (int it = 0; it < 4; ++it) {
      if (act[it]) {
        size_t o = obase[it] + (size_t)t * TOTS;
        inh_p[it] = inhib[o];
        noi_p[it] = noise[o];
      }
    }
    float cue_t = isthal ? cue[bb * NSTEP + t] : 0.f;
    float inh_i = 0.f, noi_i = 0.f, inp_i = 0.f;
    if (hasiti) {
      size_t o = obase_i + (size_t)t * TOTS;
      inh_i = inhib[o]; noi_i = noise[o];
      inp_i = inp[bb * NSTEP + t];
    }
    __syncthreads();

    // ---- dot: each thread = 4 rows x 4 batches over its k-slice
    float a[4][4];
#pragma unroll
    for (int r = 0; r < 4; ++r)
#pragma unroll
      for (int q = 0; q < 4; ++q) a[r][q] = 0.f;
    {
      const float* wp = ldsW + (ks * Kper) * strd + (rg << 2);
      const float* hp = ldsH + (ks * Kper) * 4;
      for (int q = 0; q < Kper; ++q) {
        float4 w = *(const float4*)wp;
        float4 h = *(const float4*)hp;
        wp += strd; hp += 4;
        a[0][0] = fmaf(w.x, h.x, a[0][0]); a[0][1] = fmaf(w.x, h.y, a[0][1]);
        a[0][2] = fmaf(w.x, h.z, a[0][2]); a[0][3] = fmaf(w.x, h.w, a[0][3]);
        a[1][0] = fmaf(w.y, h.x, a[1][0]); a[1][1] = fmaf(w.y, h.y, a[1][1]);
        a[1][2] = fmaf(w.y, h.z, a[1][2]); a[1][3] = fmaf(w.y, h.w, a[1][3]);
        a[2][0] = fmaf(w.z, h.x, a[2][0]); a[2][1] = fmaf(w.z, h.y, a[2][1]);
        a[2][2] = fmaf(w.z, h.z, a[2][2]); a[2][3] = fmaf(w.z, h.w, a[2][3]);
        a[3][0] = fmaf(w.w, h.x, a[3][0]); a[3][1] = fmaf(w.w, h.y, a[3][1]);
        a[3][2] = fmaf(w.w, h.z, a[3][2]); a[3][3] = fmaf(w.w, h.w, a[3][3]);
      }
    }
    // intra-wave reduce across k-slices sharing a row group
    for (int m = RG; m < 64; m <<= 1) {
#pragma unroll
      for (int r = 0; r < 4; ++r)
#pragma unroll
        for (int q = 0; q < 4; ++q)
          a[r][q] += __shfl_xor(a[r][q], m);
    }
    if ((tid & 63) < RG) {
      float* p = pacc + (wv * RG + rg) * PSTR;
#pragma unroll
      for (int r = 0; r < 4; ++r)
        *(float4*)&p[r * 4] = make_float4(a[r][0], a[r][1], a[r][2], a[r][3]);
    }
    __syncthreads();

    // ---- finals: cross-wave reduce + Euler + relu + stores
#pragma unroll
    for (int it = 0; it < 4; ++it) {
      if (act[it]) {
        int row = row0 + it * 64;
        int rg2 = row >> 2;
        int e   = ((row & 3) << 2) + b;
        float sum = pacc[(0 * RG + rg2) * PSTR + e] + pacc[(1 * RG + rg2) * PSTR + e]
                  + pacc[(2 * RG + rg2) * PSTR + e] + pacc[(3 * RG + rg2) * PSTR + e];
        float drive = sum + tonic + inh_p[it] + SCALE * noi_p[it];
        if (isthal) drive += cue_t;
        float xo = xreg[it];
        float xv = xo + DTC * (drive - xo);
        xreg[it] = xv;
        float h = fmaxf(xv, 0.f);
        hdst[hoff[it]] = h;
        out[obase[it] + (size_t)t * TOTS] = h;
      }
    }
    if (hasiti) {
      float drive = inp_i + inh_i + SCALE * noi_i;
      float xv = xreg_i + DTC * (drive - xreg_i);
      xreg_i = xv;
      float h = fmaxf(xv, 0.f);
      hdst[hoff_i] = h;
      out[obase_i + (size_t)t * TOTS] = h;
    }

    __threadfence();
    grid.sync();
  }
}

extern "C" void kernel_launch(void* const* d_in, const int* in_sizes, int n_in,
                              void* d_out, int out_size, void* d_ws, size_t ws_size,
                              hipStream_t stream) {
  const float* inp   = (const float*)d_in[0];
  const float* cue   = (const float*)d_in[1];
  const float* hn    = (const float*)d_in[2];
  const float* xn    = (const float*)d_in[3];
  const float* inhib = (const float*)d_in[4];
  const float* noise = (const float*)d_in[5];
  float* ws  = (float*)d_ws;
  float* out = (float*)d_out;

  static bool attr_done = false;
  if (!attr_done) {
    hipFuncSetAttribute((const void*)rnn_persistent,
                        hipFuncAttributeMaxDynamicSharedMemorySize, LDSB);
    attr_done = true;
  }

  build_kernel<<<(WTOTAL + 255) / 256, 256, 0, stream>>>(
      (const float*)d_in[6],  (const float*)d_in[7],  (const float*)d_in[8],
      (const float*)d_in[9],  (const float*)d_in[10], (const float*)d_in[11],
      (const float*)d_in[12], (const float*)d_in[13], (const float*)d_in[14],
      (const float*)d_in[15], (const float*)d_in[16], (const float*)d_in[17],
      (const float*)d_in[18], (const float*)d_in[19], (const float*)d_in[20],
      (const float*)d_in[21], (const float*)d_in[22], (const float*)d_in[23],
      ws);

  void* args[] = {(void*)&inp, (void*)&cue, (void*)&hn, (void*)&xn,
                  (void*)&inhib, (void*)&noise, (void*)&ws, (void*)&out};
  hipLaunchCooperativeKernel((const void*)rnn_persistent, dim3(GRIDSZ), dim3(256),
                             args, LDSB, stream);
}

// Round 2
// 7487.572 us; speedup vs baseline: 6.4665x; 6.4665x over previous
//
#include <hip/hip_runtime.h>

// ---------------------------------------------------------------------------
// Persistent RNN, round 2: kill the coherence tax.
//   - Same 26-chunk x 8-batch-group layout, W resident in LDS for 1000 steps.
//   - NO cg::grid.sync, NO __threadfence (those emit buffer_wbl2/buffer_inv =
//     whole-L2 flush per step -> round-1's 47us/step stall, VALUBusy 1.25%).
//   - Cross-block h exchange via per-group [j][4batch] buffers accessed with
//     AGENT-scope relaxed atomics (sc1 per-access coherence, no cache flush).
//   - Per-group 26-block barrier: monotonic count + gen word; release =
//     s_waitcnt vmcnt(0) + syncthreads before the arrive add.
// ws layout (floats): [Wc 836736][bar 256][hX 2*8*6704] = 3.78 MB
// ---------------------------------------------------------------------------

#define TOTS   1676
#define NSTEP  1000
#define DTC    0.01f
#define SCALE  1.41421356237e-3f   // sqrt(2*0.01)*0.01
#define NCHUNK 26
#define NGRP   8
#define GRIDSZ 208                 // 26 * 8
#define WTOTAL 836736
#define BAR_OFF 836736             // 8 groups x 32 floats (count @+0, gen @+16)
#define HX_OFF  836992             // 2 bufs x 8 groups x 6704 floats
#define HXSZ    6704               // 1676 * 4
#define PSTR   20                  // pacc row stride (floats), bank-rotated
#define LDSB   159296              // max chunk: thal/alm W+H+pacc+jmap

typedef unsigned long long u64;

// region params: 0 str, 1 gpe, 2 stn, 3 snr, 4 thal, 5 alm, 6 fsi
__device__ const int   r_R[7]     = {32, 256, 128, 64, 64, 64, 32};
__device__ const int   r_Kper[7]  = {29, 32, 32, 25, 33, 33, 21};
__device__ const int   r_K[7]     = {908, 128, 256, 384, 512, 512, 652};
__device__ const int   r_Kpad[7]  = {928, 128, 256, 400, 528, 528, 672};
__device__ const int   r_strd[7]  = {36, 260, 132, 68, 68, 68, 36};
__device__ const int   r_jbase[7] = {0, 256, 512, 768, 1024, 1280, 1600};
__device__ const float r_tonic[7] = {0.f, 1.f, 1.f, 0.f, 1.f, 0.f, 0.f};
__device__ const int   r_nseg[7]  = {5, 1, 1, 2, 2, 2, 4};
__device__ const int   r_ss[7][5] = {{0,1024,1280,1536,1600},{128,0,0,0,0},{256,0,0,0,0},
                                     {0,512,0,0,0},{768,1280,0,0,0},{1024,1280,0,0,0},
                                     {1024,1280,1536,1600,0}};
__device__ const int   r_sl[7][5] = {{256,256,256,64,76},{128,0,0,0,0},{256,0,0,0,0},
                                     {128,256,0,0,0},{256,256,0,0,0},{256,256,0,0,0},
                                     {256,256,64,76,0}};

__device__ const int c_reg[NCHUNK]   = {0,0,0,0,0,0,0,0, 1, 2,2, 3,3,3,3, 4,4,4,4, 5,5,5,5, 6,6,6};
__device__ const int c_rowb[NCHUNK]  = {0,32,64,96,128,160,192,224, 0, 0,128,
                                        0,64,128,192, 0,64,128,192, 0,64,128,192, 0,32,64};
__device__ const int c_rreal[NCHUNK] = {32,32,32,32,32,32,32,32, 256, 128,128,
                                        64,64,64,64, 64,64,64,64, 64,64,64,64, 32,32,12};
__device__ const int c_woff[NCHUNK]  = {0,33408,66816,100224,133632,167040,200448,233856,
                                        267264, 300544,334336,
                                        368128,395328,422528,449728,
                                        476928,512832,548736,584640,
                                        620544,656448,692352,728256,
                                        764160,788352,812544};

__global__ __launch_bounds__(256)
void build_kernel(const float* __restrict__ sparse,   const float* __restrict__ str2str,
                  const float* __restrict__ thal2alm, const float* __restrict__ thal2str,
                  const float* __restrict__ alm2alm,  const float* __restrict__ alm2str,
                  const float* __restrict__ alm2thal, const float* __restrict__ str2snr,
                  const float* __restrict__ str2gpe,  const float* __restrict__ gpe2stn,
                  const float* __restrict__ stn2snr,  const float* __restrict__ snr2thal,
                  const float* __restrict__ fsi2str,  const float* __restrict__ thal2fsi,
                  const float* __restrict__ alm2fsi,  const float* __restrict__ iti2fsi,
                  const float* __restrict__ fsi2fsi,  const float* __restrict__ inp_str,
                  float* __restrict__ ws)
{
  int idx = blockIdx.x * 256 + threadIdx.x;
  if (idx >= WTOTAL) {
    if (idx < WTOTAL + 256) ws[idx] = 0.f;   // zero barrier words (count/gen)
    return;
  }
  int c = 0;
  for (int cc = NCHUNK - 1; cc > 0; --cc) { if (idx >= c_woff[cc]) { c = cc; break; } }
  const int reg  = c_reg[c];
  const int strd = r_strd[reg];
  const int R    = r_R[reg];
  const int K    = r_K[reg];
  int rel = idx - c_woff[c];
  int k   = rel / strd;
  int rr  = rel - k * strd;
  float v = 0.f;
  if (rr < R && k < K) {
    int il = c_rowb[c] + rr;
    int j = 0, kk = k;
    for (int s = 0; s < r_nseg[reg]; ++s) {
      int len = r_sl[reg][s];
      if (kk < len) { j = r_ss[reg][s] + kk; break; }
      kk -= len;
    }
    switch (reg) {
      case 0: {
        if (j < 256) {
          bool same = (il < 128) == (j < 128);
          float w = fmaxf(str2str[il * 256 + j], 0.f);
          v = same ? -(sparse[il * 256 + j] * w) : 0.f;
        } else if (j < 1280) v = fmaxf(thal2str[il * 256 + (j - 1024)], 0.f);
        else if (j < 1536) { int lj = j - 1280; v = (lj < 180) ? fmaxf(alm2str[il * 256 + lj], 0.f) : 0.f; }
        else if (j < 1600) v = fmaxf(inp_str[il * 64 + (j - 1536)], 0.f);
        else               v = -fmaxf(fsi2str[il * 76 + (j - 1600)], 0.f);
      } break;
      case 1: v = -fmaxf(str2gpe[il * 256 + j], 0.f); break;
      case 2: v = -fmaxf(gpe2stn[il * 256 + (j - 256)], 0.f); break;
      case 3: v = (j < 128) ? -fmaxf(str2snr[il * 256 + j], 0.f)
                            :  fmaxf(stn2snr[il * 256 + (j - 512)], 0.f); break;
      case 4:
        if (j < 1024) v = -fmaxf(snr2thal[il * 256 + (j - 768)], 0.f);
        else { int lj = j - 1280; v = (lj < 180) ? fmaxf(alm2thal[il * 256 + lj], 0.f) : 0.f; }
        break;
      case 5:
        if (j < 1280) v = fmaxf(thal2alm[il * 256 + (j - 1024)], 0.f);
        else { int lj = j - 1280; float w = fmaxf(alm2alm[il * 256 + lj], 0.f); v = (lj >= 180) ? -w : w; }
        break;
      default:
        if (il < 76) {
          if (j < 1280)      v =  fmaxf(thal2fsi[il * 256 + (j - 1024)], 0.f);
          else if (j < 1536) v =  fmaxf(alm2fsi[il * 256 + (j - 1280)], 0.f);
          else if (j < 1600) v =  fmaxf(iti2fsi[il * 64 + (j - 1536)], 0.f);
          else               v = -fmaxf(fsi2fsi[il * 76 + (j - 1600)], 0.f);
        }
        break;
    }
  }
  ws[idx] = v;
}

__global__ __launch_bounds__(256, 1)
void rnn_persistent(const float* __restrict__ inp,   const float* __restrict__ cue,
                    const float* __restrict__ hn,    const float* __restrict__ xn,
                    const float* __restrict__ inhib, const float* __restrict__ noise,
                    float* __restrict__ ws,          float* __restrict__ out)
{
  extern __shared__ float lds[];
  const int tid = threadIdx.x;
  const int c   = blockIdx.x % NCHUNK;
  const int grp = blockIdx.x / NCHUNK;
  const int b0  = grp * 4;
  const int reg  = c_reg[c];
  const int R    = r_R[reg];
  const int Kper = r_Kper[reg];
  const int K    = r_K[reg];
  const int Kpad = r_Kpad[reg];
  const int strd = r_strd[reg];
  const int RG   = R >> 2;
  const int rgsh = (R == 32) ? 3 : (R == 64) ? 4 : (R == 128) ? 5 : 6;
  const int jout0 = r_jbase[reg] + c_rowb[c];
  const int rreal = c_rreal[c];
  const float tonic = r_tonic[reg];
  const bool isthal = (reg == 4);
  const bool hasiti = (c == 25);

  float* ldsW = lds;
  float* ldsH = lds + Kpad * strd;       // float4[Kpad]: h[k][4 batches]
  float* pacc = ldsH + Kpad * 4;         // [4 waves][RG][PSTR]
  int*   jmap = (int*)(pacc + 4 * RG * PSTR);

  int* bar_cnt = (int*)(ws + BAR_OFF) + grp * 32;
  int* bar_gen = bar_cnt + 16;
  float* hx0 = ws + HX_OFF + grp * HXSZ;
  float* hx1 = ws + HX_OFF + NGRP * HXSZ + grp * HXSZ;

  // ---- one-time: W chunk -> LDS; jmap; zero h pad region
  {
    const float* wg = ws + c_woff[c];
    const int n = Kpad * strd;           // divisible by 4
    for (int i = tid * 4; i < n; i += 1024)
      *(float4*)&ldsW[i] = *(const float4*)&wg[i];
  }
  for (int u = tid; u < K; u += 256) {
    int j = 0, kk = u;
    for (int s = 0; s < r_nseg[reg]; ++s) {
      int len = r_sl[reg][s];
      if (kk < len) { j = r_ss[reg][s] + kk; break; }
      kk -= len;
    }
    jmap[u] = j;
  }
  for (int u = K + tid; u < Kpad; u += 256)
    *(float4*)&ldsH[u * 4] = make_float4(0.f, 0.f, 0.f, 0.f);

  // ---- output ownership
  const int b    = tid & 3;
  const int bb   = b0 + b;
  const int row0 = tid >> 2;
  const int R4   = R * 4;
  bool act[4]; int hgx[4]; size_t obase[4]; float xreg[4];
#pragma unroll
  for (int it = 0; it < 4; ++it) {
    int fid = tid + it * 256;
    int row = row0 + it * 64;
    act[it] = (fid < R4) && (row < rreal);
    int j = jout0 + row;
    hgx[it]   = (j << 2) + b;
    obase[it] = (size_t)bb * NSTEP * TOTS + j;
    xreg[it]  = act[it] ? xn[bb * TOTS + j] : 0.f;
  }
  int hgx_i = 0; size_t obase_i = 0; float xreg_i = 0.f;
  if (hasiti) {                       // iti rows 1536..1599, all 256 threads
    int j = 1536 + row0;
    hgx_i   = (j << 2) + b;
    obase_i = (size_t)bb * NSTEP * TOTS + j;
    xreg_i  = xn[bb * TOTS + j];
  }

  const int rg = tid & (RG - 1);
  const int ks = tid >> rgsh;
  const int wv = tid >> 6;

  __syncthreads();   // jmap/ldsW/ldsH-pad ready

  for (int t = 0; t < NSTEP; ++t) {
    // ---- prefetch epilogue operands first (longest latency, used last)
    float inh_p[4], noi_p[4];
#pragma unroll
    for (int it = 0; it < 4; ++it) {
      if (act[it]) {
        size_t o = obase[it] + (size_t)t * TOTS;
        inh_p[it] = inhib[o];
        noi_p[it] = noise[o];
      }
    }
    float cue_t = isthal ? cue[bb * NSTEP + t] : 0.f;
    float inh_i = 0.f, noi_i = 0.f, inp_i = 0.f;
    if (hasiti) {
      size_t o = obase_i + (size_t)t * TOTS;
      inh_i = inhib[o]; noi_i = noise[o];
      inp_i = inp[bb * NSTEP + t];
    }

    // ---- stage h[k][b0..b0+3] into LDS
    if (t == 0) {
      for (int u = tid; u < K; u += 256) {
        int j = jmap[u];
        const float* hp = hn + j;
        float4 hv;
        hv.x = hp[(b0 + 0) * TOTS];
        hv.y = hp[(b0 + 1) * TOTS];
        hv.z = hp[(b0 + 2) * TOTS];
        hv.w = hp[(b0 + 3) * TOTS];
        *(float4*)&ldsH[u * 4] = hv;
      }
    } else {
      const float* hxR = (t & 1) ? hx0 : hx1;   // written at step t-1
      for (int u = tid; u < K; u += 256) {
        int j = jmap[u];
        u64* p = (u64*)(hxR + (j << 2));
        u64 lo = __hip_atomic_load(p,     __ATOMIC_RELAXED, __HIP_MEMORY_SCOPE_AGENT);
        u64 hi = __hip_atomic_load(p + 1, __ATOMIC_RELAXED, __HIP_MEMORY_SCOPE_AGENT);
        union { u64 u; float2 f; } a0, a1;
        a0.u = lo; a1.u = hi;
        *(float4*)&ldsH[u * 4] = make_float4(a0.f.x, a0.f.y, a1.f.x, a1.f.y);
      }
    }
    __syncthreads();

    // ---- dot: each thread = 4 rows x 4 batches over its k-slice
    float a[4][4];
#pragma unroll
    for (int r = 0; r < 4; ++r)
#pragma unroll
      for (int q = 0; q < 4; ++q) a[r][q] = 0.f;
    {
      const float* wp = ldsW + (ks * Kper) * strd + (rg << 2);
      const float* hp = ldsH + (ks * Kper) * 4;
      for (int q = 0; q < Kper; ++q) {
        float4 w = *(const float4*)wp;
        float4 h = *(const float4*)hp;
        wp += strd; hp += 4;
        a[0][0] = fmaf(w.x, h.x, a[0][0]); a[0][1] = fmaf(w.x, h.y, a[0][1]);
        a[0][2] = fmaf(w.x, h.z, a[0][2]); a[0][3] = fmaf(w.x, h.w, a[0][3]);
        a[1][0] = fmaf(w.y, h.x, a[1][0]); a[1][1] = fmaf(w.y, h.y, a[1][1]);
        a[1][2] = fmaf(w.y, h.z, a[1][2]); a[1][3] = fmaf(w.y, h.w, a[1][3]);
        a[2][0] = fmaf(w.z, h.x, a[2][0]); a[2][1] = fmaf(w.z, h.y, a[2][1]);
        a[2][2] = fmaf(w.z, h.z, a[2][2]); a[2][3] = fmaf(w.z, h.w, a[2][3]);
        a[3][0] = fmaf(w.w, h.x, a[3][0]); a[3][1] = fmaf(w.w, h.y, a[3][1]);
        a[3][2] = fmaf(w.w, h.z, a[3][2]); a[3][3] = fmaf(w.w, h.w, a[3][3]);
      }
    }
    for (int m = RG; m < 64; m <<= 1) {
#pragma unroll
      for (int r = 0; r < 4; ++r)
#pragma unroll
        for (int q = 0; q < 4; ++q)
          a[r][q] += __shfl_xor(a[r][q], m);
    }
    if ((tid & 63) < RG) {
      float* p = pacc + (wv * RG + rg) * PSTR;
#pragma unroll
      for (int r = 0; r < 4; ++r)
        *(float4*)&p[r * 4] = make_float4(a[r][0], a[r][1], a[r][2], a[r][3]);
    }
    __syncthreads();

    // ---- finals: cross-wave reduce + Euler + relu + publish h
    float* hxW = (t & 1) ? hx1 : hx0;
#pragma unroll
    for (int it = 0; it < 4; ++it) {
      if (act[it]) {
        int row = row0 + it * 64;
        int rg2 = row >> 2;
        int e   = ((row & 3) << 2) + b;
        float sum = pacc[(0 * RG + rg2) * PSTR + e] + pacc[(1 * RG + rg2) * PSTR + e]
                  + pacc[(2 * RG + rg2) * PSTR + e] + pacc[(3 * RG + rg2) * PSTR + e];
        float drive = sum + tonic + inh_p[it] + SCALE * noi_p[it];
        if (isthal) drive += cue_t;
        float xo = xreg[it];
        float xv = xo + DTC * (drive - xo);
        xreg[it] = xv;
        float h = fmaxf(xv, 0.f);
        __hip_atomic_store(&hxW[hgx[it]], h, __ATOMIC_RELAXED, __HIP_MEMORY_SCOPE_AGENT);
        out[obase[it] + (size_t)t * TOTS] = h;
      }
    }
    if (hasiti) {
      float drive = inp_i + inh_i + SCALE * noi_i;
      float xv = xreg_i + DTC * (drive - xreg_i);
      xreg_i = xv;
      float h = fmaxf(xv, 0.f);
      __hip_atomic_store(&hxW[hgx_i], h, __ATOMIC_RELAXED, __HIP_MEMORY_SCOPE_AGENT);
      out[obase_i + (size_t)t * TOTS] = h;
    }

    // ---- per-group barrier (release: all stores at coherence point first)
    if (t + 1 < NSTEP) {
      asm volatile("s_waitcnt vmcnt(0)" ::: "memory");
      __syncthreads();
      if (tid == 0) {
        const int need = NCHUNK * (t + 1);
        int old = __hip_atomic_fetch_add(bar_cnt, 1, __ATOMIC_RELAXED, __HIP_MEMORY_SCOPE_AGENT);
        if (old + 1 == need) {
          __hip_atomic_store(bar_gen, t + 1, __ATOMIC_RELAXED, __HIP_MEMORY_SCOPE_AGENT);
        } else {
          while (__hip_atomic_load(bar_gen, __ATOMIC_RELAXED, __HIP_MEMORY_SCOPE_AGENT) < t + 1)
            __builtin_amdgcn_s_sleep(1);
        }
      }
      __syncthreads();
      asm volatile("" ::: "memory");
    }
  }
}

extern "C" void kernel_launch(void* const* d_in, const int* in_sizes, int n_in,
                              void* d_out, int out_size, void* d_ws, size_t ws_size,
                              hipStream_t stream) {
  const float* inp   = (const float*)d_in[0];
  const float* cue   = (const float*)d_in[1];
  const float* hn    = (const float*)d_in[2];
  const float* xn    = (const float*)d_in[3];
  const float* inhib = (const float*)d_in[4];
  const float* noise = (const float*)d_in[5];
  float* ws  = (float*)d_ws;
  float* out = (float*)d_out;

  static bool attr_done = false;
  if (!attr_done) {
    hipFuncSetAttribute((const void*)rnn_persistent,
                        hipFuncAttributeMaxDynamicSharedMemorySize, LDSB);
    attr_done = true;
  }

  build_kernel<<<(WTOTAL + 256 + 255) / 256, 256, 0, stream>>>(
      (const float*)d_in[6],  (const float*)d_in[7],  (const float*)d_in[8],
      (const float*)d_in[9],  (const float*)d_in[10], (const float*)d_in[11],
      (const float*)d_in[12], (const float*)d_in[13], (const float*)d_in[14],
      (const float*)d_in[15], (const float*)d_in[16], (const float*)d_in[17],
      (const float*)d_in[18], (const float*)d_in[19], (const float*)d_in[20],
      (const float*)d_in[21], (const float*)d_in[22], (const float*)d_in[23],
      ws);

  void* args[] = {(void*)&inp, (void*)&cue, (void*)&hn, (void*)&xn,
                  (void*)&inhib, (void*)&noise, (void*)&ws, (void*)&out};
  hipLaunchCooperativeKernel((const void*)rnn_persistent, dim3(GRIDSZ), dim3(256),
                             args, LDSB, stream);
}